// Round 1
// baseline (2533.982 us; speedup 1.0000x reference)
//
#include <hip/hip_runtime.h>
#include <hip/hip_bf16.h>

// SparseBottleneck: c1 = lrelu(sconv(feats,W1)); c2 = lrelu(c1@W2); out = sconv(c2,W3)*mask
// N=200000, C=128, K=27, M=100000, NEG_SLOPE=0.2

typedef __attribute__((ext_vector_type(8))) short short8;
typedef __attribute__((ext_vector_type(4))) float f32x4;

#define CDIM 128
#define BM   128
#define NEG_SLOPE 0.2f

__device__ __forceinline__ unsigned short f2bf(float x) {
    union { float f; unsigned u; } un; un.f = x;
    unsigned r = un.u + 0x7fffu + ((un.u >> 16) & 1u);   // RNE
    return (unsigned short)(r >> 16);
}

__device__ __forceinline__ float lrelu(float x) {
    return x >= 0.f ? x : NEG_SLOPE * x;
}

// swizzled LDS element index: row-major 128 cols, 8-elem chunk XOR'd by (r&15).
// All accesses use 8-aligned columns, so a 16B chunk stays contiguous.
__device__ __forceinline__ int swz(int r, int c) {
    return (r << 7) + ((((c >> 3) ^ (r & 15)) << 3));
}

// ---------------------------------------------------------------- converters
__global__ void cvt_feats_kernel(const float* __restrict__ in,
                                 unsigned short* __restrict__ out, int n4) {
    int i = blockIdx.x * blockDim.x + threadIdx.x;
    if (i >= n4) return;
    float4 v = reinterpret_cast<const float4*>(in)[i];
    ushort4 o;
    o.x = f2bf(v.x); o.y = f2bf(v.y); o.z = f2bf(v.z); o.w = f2bf(v.w);
    reinterpret_cast<ushort4*>(out)[i] = o;
}

// W1/W3: [K][Cin][Cout] -> Wt[K][Cout][Cin] bf16 ; W2: [Cin][Cout] -> W2t[Cout][Cin]
__global__ void cvt_weights_kernel(const float* __restrict__ W1,
                                   const float* __restrict__ W2,
                                   const float* __restrict__ W3,
                                   unsigned short* __restrict__ W1t,
                                   unsigned short* __restrict__ W2t,
                                   unsigned short* __restrict__ W3t) {
    const int KW = 27 * 128 * 128;                 // 442368
    int t = blockIdx.x * blockDim.x + threadIdx.x;
    if (t < KW) {
        int k = t >> 14, r = t & 16383, n = r >> 7, kk = r & 127;
        W1t[t] = f2bf(W1[(k << 14) + (kk << 7) + n]);
    } else if (t < 2 * KW) {
        int t2 = t - KW;
        int k = t2 >> 14, r = t2 & 16383, n = r >> 7, kk = r & 127;
        W3t[t2] = f2bf(W3[(k << 14) + (kk << 7) + n]);
    } else if (t < 2 * KW + 16384) {
        int t2 = t - 2 * KW;
        int n = t2 >> 7, kk = t2 & 127;
        W2t[t2] = f2bf(W2[(kk << 7) + n]);
    }
}

// ---------------------------------------------------------------- sparse conv
// One block: tap k = blockIdx.y, rows mbase..mbase+127 of the M gather list.
// out[out_map[k][m]] += bf16(A[in_map[k][m]]) @ W_k   (atomic accumulate, fp32)
__global__ __launch_bounds__(256, 2)
void sconv_kernel(const unsigned short* __restrict__ A,     // [N,128] bf16
                  const unsigned short* __restrict__ Wt,    // [K,128,128] bf16 [k][n][kk]
                  const int* __restrict__ in_map,           // [K,M]
                  const int* __restrict__ out_map,          // [K,M]
                  float* __restrict__ out,                  // [N,128] fp32 accum
                  int M) {
    const int k     = blockIdx.y;
    const int mbase = blockIdx.x * BM;
    const int tid   = threadIdx.x;

    __shared__ unsigned short lA[BM * CDIM];   // 32 KB, swizzled
    __shared__ unsigned short lW[CDIM * CDIM]; // 32 KB, swizzled

    // stage W_k (16384 bf16): 256 thr x 8 elem x 8 iters, coalesced 16B
    const unsigned short* wk = Wt + (size_t)k * 16384;
    #pragma unroll
    for (int i = 0; i < 8; ++i) {
        int flat = (i * 256 + tid) * 8;
        int row = flat >> 7, col = flat & 127;
        short8 v = *reinterpret_cast<const short8*>(wk + flat);
        *reinterpret_cast<short8*>(&lW[swz(row, col)]) = v;
    }

    // gather A rows: 16 thr/row, 16 rows/pass, 8 passes
    const int* imk = in_map + (size_t)k * M;
    #pragma unroll
    for (int p = 0; p < 8; ++p) {
        int r = p * 16 + (tid >> 4);
        int c = (tid & 15) * 8;
        int m = mbase + r;
        short8 v = {0, 0, 0, 0, 0, 0, 0, 0};
        if (m < M) {
            int arow = __ldg(imk + m);
            v = *reinterpret_cast<const short8*>(A + (size_t)arow * CDIM + c);
        }
        *reinterpret_cast<short8*>(&lA[swz(r, c)]) = v;
    }
    __syncthreads();

    const int wid  = tid >> 6, lane = tid & 63;
    const int wr   = (wid >> 1) * 64, wc = (wid & 1) * 64;
    const int lrow = lane & 15, quad = lane >> 4;

    f32x4 acc[4][4];
    #pragma unroll
    for (int i = 0; i < 4; ++i)
        #pragma unroll
        for (int j = 0; j < 4; ++j)
            acc[i][j] = {0.f, 0.f, 0.f, 0.f};

    #pragma unroll
    for (int s = 0; s < 4; ++s) {
        const int kf = s * 32 + quad * 8;
        short8 a[4], b[4];
        #pragma unroll
        for (int i = 0; i < 4; ++i)
            a[i] = *reinterpret_cast<const short8*>(&lA[swz(wr + i * 16 + lrow, kf)]);
        #pragma unroll
        for (int j = 0; j < 4; ++j)
            b[j] = *reinterpret_cast<const short8*>(&lW[swz(wc + j * 16 + lrow, kf)]);
        #pragma unroll
        for (int i = 0; i < 4; ++i)
            #pragma unroll
            for (int j = 0; j < 4; ++j)
                acc[i][j] = __builtin_amdgcn_mfma_f32_16x16x32_bf16(a[i], b[j], acc[i][j], 0, 0, 0);
    }

    // scatter-add: C/D layout col=lane&15, row=quad*4+reg
    const int* omk = out_map + (size_t)k * M;
    #pragma unroll
    for (int i = 0; i < 4; ++i) {
        #pragma unroll
        for (int reg = 0; reg < 4; ++reg) {
            int m = mbase + wr + i * 16 + quad * 4 + reg;
            if (m < M) {
                int orow = __ldg(omk + m);
                float* dst = out + (size_t)orow * CDIM + wc + lrow;
                #pragma unroll
                for (int j = 0; j < 4; ++j)
                    unsafeAtomicAdd(dst + j * 16, acc[i][j][reg]);
            }
        }
    }
}

// ---------------------------------------------------------------- dense conv2
// c2 = bf16(lrelu( lrelu(c1) @ W2 ))  — reads fp32 c1 (raw conv1 accum), fuses both lrelus
__global__ __launch_bounds__(256, 2)
void conv2_kernel(const float* __restrict__ c1,             // [N,128] fp32 (pre-lrelu)
                  const unsigned short* __restrict__ W2t,   // [128,128] bf16 [n][kk]
                  unsigned short* __restrict__ c2,          // [N,128] bf16
                  int M) {
    const int mbase = blockIdx.x * BM;
    const int tid   = threadIdx.x;

    __shared__ unsigned short lA[BM * CDIM];
    __shared__ unsigned short lW[CDIM * CDIM];

    #pragma unroll
    for (int i = 0; i < 8; ++i) {
        int flat = (i * 256 + tid) * 8;
        int row = flat >> 7, col = flat & 127;
        short8 v = *reinterpret_cast<const short8*>(W2t + flat);
        *reinterpret_cast<short8*>(&lW[swz(row, col)]) = v;
    }

    #pragma unroll
    for (int p = 0; p < 8; ++p) {
        int r = p * 16 + (tid >> 4);
        int c = (tid & 15) * 8;
        int m = mbase + r;
        unsigned short vv[8];
        if (m < M) {
            const float4* src = reinterpret_cast<const float4*>(c1 + (size_t)m * CDIM + c);
            float4 x0 = src[0], x1 = src[1];
            vv[0] = f2bf(lrelu(x0.x)); vv[1] = f2bf(lrelu(x0.y));
            vv[2] = f2bf(lrelu(x0.z)); vv[3] = f2bf(lrelu(x0.w));
            vv[4] = f2bf(lrelu(x1.x)); vv[5] = f2bf(lrelu(x1.y));
            vv[6] = f2bf(lrelu(x1.z)); vv[7] = f2bf(lrelu(x1.w));
        } else {
            #pragma unroll
            for (int q = 0; q < 8; ++q) vv[q] = 0;
        }
        short8 v;
        #pragma unroll
        for (int q = 0; q < 8; ++q) v[q] = (short)vv[q];
        *reinterpret_cast<short8*>(&lA[swz(r, c)]) = v;
    }
    __syncthreads();

    const int wid  = tid >> 6, lane = tid & 63;
    const int wr   = (wid >> 1) * 64, wc = (wid & 1) * 64;
    const int lrow = lane & 15, quad = lane >> 4;

    f32x4 acc[4][4];
    #pragma unroll
    for (int i = 0; i < 4; ++i)
        #pragma unroll
        for (int j = 0; j < 4; ++j)
            acc[i][j] = {0.f, 0.f, 0.f, 0.f};

    #pragma unroll
    for (int s = 0; s < 4; ++s) {
        const int kf = s * 32 + quad * 8;
        short8 a[4], b[4];
        #pragma unroll
        for (int i = 0; i < 4; ++i)
            a[i] = *reinterpret_cast<const short8*>(&lA[swz(wr + i * 16 + lrow, kf)]);
        #pragma unroll
        for (int j = 0; j < 4; ++j)
            b[j] = *reinterpret_cast<const short8*>(&lW[swz(wc + j * 16 + lrow, kf)]);
        #pragma unroll
        for (int i = 0; i < 4; ++i)
            #pragma unroll
            for (int j = 0; j < 4; ++j)
                acc[i][j] = __builtin_amdgcn_mfma_f32_16x16x32_bf16(a[i], b[j], acc[i][j], 0, 0, 0);
    }

    #pragma unroll
    for (int i = 0; i < 4; ++i) {
        #pragma unroll
        for (int reg = 0; reg < 4; ++reg) {
            int m = mbase + wr + i * 16 + quad * 4 + reg;
            if (m < M) {
                unsigned short* dst = c2 + (size_t)m * CDIM + wc + lrow;
                #pragma unroll
                for (int j = 0; j < 4; ++j)
                    dst[j * 16] = f2bf(lrelu(acc[i][j][reg]));
            }
        }
    }
}

// ---------------------------------------------------------------- mask epilogue
__global__ void mask_mul_kernel(float* __restrict__ out,
                                const float* __restrict__ mask, int n4) {
    int i = blockIdx.x * blockDim.x + threadIdx.x;
    if (i >= n4) return;
    int row = i >> 5;                       // 32 float4 per 128-wide row
    float m = mask[row];
    float4 v = reinterpret_cast<float4*>(out)[i];
    v.x *= m; v.y *= m; v.z *= m; v.w *= m;
    reinterpret_cast<float4*>(out)[i] = v;
}

// ---------------------------------------------------------------- launch
extern "C" void kernel_launch(void* const* d_in, const int* in_sizes, int n_in,
                              void* d_out, int out_size, void* d_ws, size_t ws_size,
                              hipStream_t stream) {
    const float* feats   = (const float*)d_in[0];
    const float* W1      = (const float*)d_in[1];
    const float* W2      = (const float*)d_in[2];
    const float* W3      = (const float*)d_in[3];
    const int*   in_map  = (const int*)d_in[4];
    const int*   out_map = (const int*)d_in[5];
    const float* mask    = (const float*)d_in[6];
    float*       out     = (float*)d_out;

    const int K = 27;
    const int N = in_sizes[0] / CDIM;      // 200000
    const int M = in_sizes[4] / K;         // 100000

    // workspace layout (bf16 = ushort)
    unsigned short* feats_bf = (unsigned short*)d_ws;
    unsigned short* c2_bf    = feats_bf + (size_t)N * CDIM;
    unsigned short* W1t      = c2_bf + (size_t)N * CDIM;
    unsigned short* W3t      = W1t + (size_t)K * CDIM * CDIM;
    unsigned short* W2t      = W3t + (size_t)K * CDIM * CDIM;
    size_t need = ((size_t)2 * N * CDIM + (size_t)2 * K * CDIM * CDIM + CDIM * CDIM) * 2;
    if (ws_size < need) return;  // would rather fail loudly (zero/poison output) than corrupt

    const int n4 = N * CDIM / 4;
    cvt_feats_kernel<<<(n4 + 255) / 256, 256, 0, stream>>>(feats, feats_bf, n4);
    const int wtot = 2 * K * CDIM * CDIM + CDIM * CDIM;
    cvt_weights_kernel<<<(wtot + 255) / 256, 256, 0, stream>>>(W1, W2, W3, W1t, W2t, W3t);

    hipMemsetAsync(d_out, 0, (size_t)N * CDIM * sizeof(float), stream);

    dim3 gs((M + BM - 1) / BM, K);
    sconv_kernel<<<gs, 256, 0, stream>>>(feats_bf, W1t, in_map, out_map, out, M);

    conv2_kernel<<<(N + BM - 1) / BM, 256, 0, stream>>>(out, W2t, c2_bf, N);

    hipMemsetAsync(d_out, 0, (size_t)N * CDIM * sizeof(float), stream);
    sconv_kernel<<<gs, 256, 0, stream>>>(c2_bf, W3t, in_map, out_map, out, M);

    mask_mul_kernel<<<(n4 + 255) / 256, 256, 0, stream>>>(out, mask, n4);
}